// Round 1
// baseline (466.992 us; speedup 1.0000x reference)
//
#include <hip/hip_runtime.h>
#include <hip/hip_bf16.h>
#include <stdint.h>

// Problem constants (fixed by the reference)
#define N_EDGES   800000
#define N_NODESC  50000
#define HID       128

typedef __attribute__((ext_vector_type(8))) short bf16x8;  // 8 bf16 = 4 VGPRs (MFMA A/B frag)
typedef __attribute__((ext_vector_type(4))) short bf16x4;
typedef __attribute__((ext_vector_type(4))) float f32x4;   // MFMA C/D frag

__device__ __forceinline__ short f2bf(float f) {
    union { float f; uint32_t u; } v; v.f = f;
    uint32_t r = v.u + 0x7FFFu + ((v.u >> 16) & 1u);   // round-to-nearest-even
    return (short)(r >> 16);
}
__device__ __forceinline__ float bf2f(short s) {
    union { uint32_t u; float f; } v;
    v.u = ((uint32_t)(uint16_t)s) << 16;
    return v.f;
}

// ---------------- workspace layout ----------------
// PQ  : bf16 [50000][1024]  (cols 0..511 = emb@W1_top "P", 512..1023 = emb@W1_bot "Q")
// W1s : bf16 frag-major, 4*64 frags x 64 lanes x 8   (B-frags of W1cat [128,1024])
// W2s : bf16 frag-major, 16*8 frags x 64 lanes x 8   (B-frags of W2 [512,128])
#define PQ_OFF   0UL
#define W1S_OFF  102400000UL                 // 50000*1024*2
#define W2S_OFF  (W1S_OFF + 262144UL)        // + 128*1024*2
// total ws needed: 102,793,216 bytes

// ============ kernel 0: weight convert + B-fragment swizzle ============
// B-frag for 16x16x32 bf16: lane l holds B[k = kc*32 + (l>>4)*8 + j][n = nt*16 + (l&15)], j=0..7
__global__ __launch_bounds__(256) void swizzle_kernel(const float* __restrict__ W1,
                                                      const float* __restrict__ W2,
                                                      short* __restrict__ W1s,
                                                      short* __restrict__ W2s) {
    int t = blockIdx.x * 256 + threadIdx.x;
    int lane = t & 63;
    int kq = lane >> 4;       // 0..3
    int nn = lane & 15;
    if (t < 16384) {          // W1cat: K=128, N=1024 -> kc 0..3, nt 0..63
        int frag = t >> 6;
        int kc = frag >> 6;
        int nt = frag & 63;
        int n = nt * 16 + nn;
        int kbase = kc * 32 + kq * 8;
        bf16x8 v;
        #pragma unroll
        for (int j = 0; j < 8; ++j) {
            int k = kbase + j;
            float f = (n < 512) ? W1[k * 512 + n] : W1[(128 + k) * 512 + (n - 512)];
            v[j] = f2bf(f);
        }
        *(bf16x8*)(W1s + frag * 512 + lane * 8) = v;
    } else if (t < 24576) {   // W2: K=512, N=128 -> kc 0..15, nt 0..7
        int t2 = t - 16384;
        int frag = t2 >> 6;
        int kc = frag >> 3;
        int nt = frag & 7;
        int n = nt * 16 + nn;
        int kbase = kc * 32 + kq * 8;
        bf16x8 v;
        #pragma unroll
        for (int j = 0; j < 8; ++j) v[j] = f2bf(W2[(kbase + j) * HID + n]);
        *(bf16x8*)(W2s + frag * 512 + lane * 8) = v;
    }
}

// ============ kernel 1: PQ = emb @ W1cat  (bf16 MFMA, f32 acc, bf16 out) ============
// grid 3125 x 256: block = 16 node rows, 4 independent waves each owning 256 of 1024 cols.
__global__ __launch_bounds__(256) void precompute_kernel(const float* __restrict__ emb,
                                                         const short* __restrict__ W1s,
                                                         short* __restrict__ PQ) {
    __shared__ short ldsA[4][16][136];   // per-wave copy, +8 pad (272B row stride: 2-way banks)
    int lane = threadIdx.x & 63;
    int w = threadIdx.x >> 6;
    int nb = blockIdx.x * 16;

    // stage A tile (16 rows x 128 f32 contiguous) -> bf16 LDS, per-wave redundant copy
    const float* src = emb + (size_t)nb * 128;
    #pragma unroll
    for (int q = 0; q < 8; ++q) {
        int flat = q * 256 + lane * 4;
        f32x4 v = *(const f32x4*)(src + flat);
        int r = flat >> 7, c = flat & 127;
        bf16x4 b;
        b[0] = f2bf(v[0]); b[1] = f2bf(v[1]); b[2] = f2bf(v[2]); b[3] = f2bf(v[3]);
        *(bf16x4*)(&ldsA[w][r][c]) = b;
    }

    f32x4 acc[16];
    #pragma unroll
    for (int i = 0; i < 16; ++i) acc[i] = (f32x4){0.f, 0.f, 0.f, 0.f};

    int m = lane & 15;
    int kq = lane >> 4;
    for (int kc = 0; kc < 4; ++kc) {
        bf16x8 a = *(const bf16x8*)(&ldsA[w][m][kc * 32 + kq * 8]);
        #pragma unroll
        for (int nt = 0; nt < 16; ++nt) {
            int frag = kc * 64 + (w * 16 + nt);
            bf16x8 b = *(const bf16x8*)(W1s + frag * 512 + lane * 8);
            acc[nt] = __builtin_amdgcn_mfma_f32_16x16x32_bf16(a, b, acc[nt], 0, 0, 0);
        }
    }

    // C/D layout: col = lane&15, row = (lane>>4)*4 + r
    #pragma unroll
    for (int nt = 0; nt < 16; ++nt) {
        #pragma unroll
        for (int r = 0; r < 4; ++r) {
            int node = nb + kq * 4 + r;
            int n = w * 256 + nt * 16 + m;
            PQ[(size_t)node * 1024 + n] = f2bf(acc[nt][r]);
        }
    }
}

// ============ kernel 2: per-edge fused layer1(gather+add) + layer2(MFMA) + layer3 ============
// grid 12500 x 256: each wave independently owns 16 edges (no barriers in kernel).
__global__ __launch_bounds__(256) void edge_kernel(const short* __restrict__ PQ,
                                                   const int* __restrict__ ei,
                                                   const float* __restrict__ b1,
                                                   const short* __restrict__ W2s,
                                                   const float* __restrict__ b2,
                                                   const float* __restrict__ W3,
                                                   const float* __restrict__ b3,
                                                   float* __restrict__ out) {
    __shared__ short x1[4][16][520];   // per-wave 16 x 512 bf16, +8 pad (1040B stride: 2-way banks)
    int lane = threadIdx.x & 63;
    int w = threadIdx.x >> 6;
    int e0 = blockIdx.x * 64 + w * 16;

    // b1 slice for this lane's k range (k = lane*8 .. +7)
    f32x4 b1a = *(const f32x4*)(b1 + lane * 8);
    f32x4 b1b = *(const f32x4*)(b1 + lane * 8 + 4);

    // 32 edge indices (16 col + 16 row) in one lane-parallel load, broadcast via shfl
    int idx0 = 0;
    if (lane < 32) idx0 = ei[(lane >> 4) * N_EDGES + e0 + (lane & 15)];

    // ---- layer 1: gather P[col] + Q[row] + b1, relu, bf16 -> LDS ----
    #pragma unroll 4
    for (int i = 0; i < 16; ++i) {
        int ce = __shfl(idx0, i, 64);
        int re = __shfl(idx0, 16 + i, 64);
        bf16x8 p = *(const bf16x8*)(PQ + (size_t)ce * 1024 + lane * 8);
        bf16x8 q = *(const bf16x8*)(PQ + (size_t)re * 1024 + 512 + lane * 8);
        bf16x8 s;
        #pragma unroll
        for (int j = 0; j < 8; ++j) {
            float f = bf2f(p[j]) + bf2f(q[j]) + (j < 4 ? b1a[j] : b1b[j - 4]);
            f = f > 0.f ? f : 0.f;
            s[j] = f2bf(f);
        }
        *(bf16x8*)(&x1[w][i][lane * 8]) = s;
    }

    // ---- layer 2: [16,512] @ [512,128] via 16x16x32 MFMA ----
    f32x4 acc[8];
    #pragma unroll
    for (int nt = 0; nt < 8; ++nt) acc[nt] = (f32x4){0.f, 0.f, 0.f, 0.f};
    int m = lane & 15;
    int kq = lane >> 4;
    for (int kc = 0; kc < 16; ++kc) {
        bf16x8 a = *(const bf16x8*)(&x1[w][m][kc * 32 + kq * 8]);
        #pragma unroll
        for (int nt = 0; nt < 8; ++nt) {
            bf16x8 b = *(const bf16x8*)(W2s + (kc * 8 + nt) * 512 + lane * 8);
            acc[nt] = __builtin_amdgcn_mfma_f32_16x16x32_bf16(a, b, acc[nt], 0, 0, 0);
        }
    }

    // ---- epilogue: +b2, relu, dot with W3, +b3 (all f32) ----
    float b2v[8], w3v[8];
    #pragma unroll
    for (int nt = 0; nt < 8; ++nt) {
        b2v[nt] = b2[nt * 16 + m];
        w3v[nt] = W3[nt * 16 + m];
    }
    float b3s = b3[0];
    float partial[4] = {0.f, 0.f, 0.f, 0.f};
    #pragma unroll
    for (int nt = 0; nt < 8; ++nt) {
        #pragma unroll
        for (int r = 0; r < 4; ++r) {
            float x2 = acc[nt][r] + b2v[nt];           // C row = kq*4+r, col = nt*16+m
            x2 = x2 > 0.f ? x2 : 0.f;
            partial[r] += x2 * w3v[nt];
        }
    }
    #pragma unroll
    for (int r = 0; r < 4; ++r) {
        #pragma unroll
        for (int off = 1; off < 16; off <<= 1)
            partial[r] += __shfl_xor(partial[r], off, 64);
        if (m == 0) out[e0 + kq * 4 + r] = partial[r] + b3s;
    }
}

extern "C" void kernel_launch(void* const* d_in, const int* in_sizes, int n_in,
                              void* d_out, int out_size, void* d_ws, size_t ws_size,
                              hipStream_t stream) {
    const float* emb = (const float*)d_in[0];
    const int*   ei  = (const int*)d_in[1];
    const float* W1  = (const float*)d_in[2];
    const float* b1  = (const float*)d_in[3];
    const float* W2  = (const float*)d_in[4];
    const float* b2  = (const float*)d_in[5];
    const float* W3  = (const float*)d_in[6];
    const float* b3  = (const float*)d_in[7];
    float* out = (float*)d_out;

    short* PQ  = (short*)((char*)d_ws + PQ_OFF);
    short* W1s = (short*)((char*)d_ws + W1S_OFF);
    short* W2s = (short*)((char*)d_ws + W2S_OFF);

    swizzle_kernel<<<96, 256, 0, stream>>>(W1, W2, W1s, W2s);
    precompute_kernel<<<N_NODESC / 16, 256, 0, stream>>>(emb, W1s, PQ);   // 3125 blocks
    edge_kernel<<<N_EDGES / 64, 256, 0, stream>>>(PQ, ei, b1, W2s, b2, W3, b3, out);  // 12500 blocks
}

// Round 2
// 430.622 us; speedup vs baseline: 1.0845x; 1.0845x over previous
//
#include <hip/hip_runtime.h>
#include <hip/hip_bf16.h>
#include <stdint.h>

// Problem constants (fixed by the reference)
#define N_EDGES   800000
#define N_NODESC  50000
#define HID       128

typedef __attribute__((ext_vector_type(8))) short bf16x8;  // 8 bf16 = 4 VGPRs (MFMA A/B frag)
typedef __attribute__((ext_vector_type(4))) short bf16x4;
typedef __attribute__((ext_vector_type(4))) float f32x4;   // MFMA C/D frag

__device__ __forceinline__ short f2bf(float f) {
    union { float f; uint32_t u; } v; v.f = f;
    uint32_t r = v.u + 0x7FFFu + ((v.u >> 16) & 1u);   // round-to-nearest-even
    return (short)(r >> 16);
}
__device__ __forceinline__ float bf2f(short s) {
    union { uint32_t u; float f; } v;
    v.u = ((uint32_t)(uint16_t)s) << 16;
    return v.f;
}

// ---------------- workspace layout ----------------
// PQ  : bf16 [50000][1024]  (cols 0..511 = emb@W1_top + b1 "P'", 512..1023 = emb@W1_bot "Q")
// W1s : bf16 frag-major, 4*64 frags x 64 lanes x 8   (B-frags of W1cat [128,1024])
// W2s : bf16 frag-major, 16*8 frags x 64 lanes x 8   (B-frags of W2 [512,128])
#define PQ_OFF   0UL
#define W1S_OFF  102400000UL                 // 50000*1024*2
#define W2S_OFF  (W1S_OFF + 262144UL)        // + 128*1024*2
// total ws needed: 102,793,216 bytes

// ============ kernel 0: weight convert + B-fragment swizzle ============
// B-frag for 16x16x32 bf16: lane l holds B[k = kc*32 + (l>>4)*8 + j][n = nt*16 + (l&15)], j=0..7
__global__ __launch_bounds__(256) void swizzle_kernel(const float* __restrict__ W1,
                                                      const float* __restrict__ W2,
                                                      short* __restrict__ W1s,
                                                      short* __restrict__ W2s) {
    int t = blockIdx.x * 256 + threadIdx.x;
    int lane = t & 63;
    int kq = lane >> 4;       // 0..3
    int nn = lane & 15;
    if (t < 16384) {          // W1cat: K=128, N=1024 -> kc 0..3, nt 0..63
        int frag = t >> 6;
        int kc = frag >> 6;
        int nt = frag & 63;
        int n = nt * 16 + nn;
        int kbase = kc * 32 + kq * 8;
        bf16x8 v;
        #pragma unroll
        for (int j = 0; j < 8; ++j) {
            int k = kbase + j;
            float f = (n < 512) ? W1[k * 512 + n] : W1[(128 + k) * 512 + (n - 512)];
            v[j] = f2bf(f);
        }
        *(bf16x8*)(W1s + frag * 512 + lane * 8) = v;
    } else if (t < 24576) {   // W2: K=512, N=128 -> kc 0..15, nt 0..7
        int t2 = t - 16384;
        int frag = t2 >> 6;
        int kc = frag >> 3;
        int nt = frag & 7;
        int n = nt * 16 + nn;
        int kbase = kc * 32 + kq * 8;
        bf16x8 v;
        #pragma unroll
        for (int j = 0; j < 8; ++j) v[j] = f2bf(W2[(kbase + j) * HID + n]);
        *(bf16x8*)(W2s + frag * 512 + lane * 8) = v;
    }
}

// ============ kernel 1: PQ = emb @ W1cat (+b1 on P half)  — LDS-free ============
// grid 3125 x 256: block = 16 node rows, 4 waves each owning 256 of 1024 cols.
// Each wave loads its own A-frags directly from emb (emb is L2-resident, redundancy cheap).
__global__ __launch_bounds__(256) void precompute_kernel(const float* __restrict__ emb,
                                                         const short* __restrict__ W1s,
                                                         const float* __restrict__ b1,
                                                         short* __restrict__ PQ) {
    int lane = threadIdx.x & 63;
    int w = threadIdx.x >> 6;
    int nb = blockIdx.x * 16;
    int m = lane & 15;
    int kq = lane >> 4;

    f32x4 acc[16];
    #pragma unroll
    for (int i = 0; i < 16; ++i) acc[i] = (f32x4){0.f, 0.f, 0.f, 0.f};

    const float* arow = emb + (size_t)(nb + m) * 128 + kq * 8;
    #pragma unroll
    for (int kc = 0; kc < 4; ++kc) {
        f32x4 a0 = *(const f32x4*)(arow + kc * 32);
        f32x4 a1 = *(const f32x4*)(arow + kc * 32 + 4);
        bf16x8 a;
        a[0] = f2bf(a0[0]); a[1] = f2bf(a0[1]); a[2] = f2bf(a0[2]); a[3] = f2bf(a0[3]);
        a[4] = f2bf(a1[0]); a[5] = f2bf(a1[1]); a[6] = f2bf(a1[2]); a[7] = f2bf(a1[3]);
        #pragma unroll
        for (int nt = 0; nt < 16; ++nt) {
            int frag = kc * 64 + (w * 16 + nt);
            bf16x8 b = *(const bf16x8*)(W1s + frag * 512 + lane * 8);
            acc[nt] = __builtin_amdgcn_mfma_f32_16x16x32_bf16(a, b, acc[nt], 0, 0, 0);
        }
    }

    // C/D layout: col = lane&15, row = (lane>>4)*4 + r.  Fold b1 into the P half (n<512).
    #pragma unroll
    for (int nt = 0; nt < 16; ++nt) {
        int n = w * 256 + nt * 16 + m;
        float bias = (n < 512) ? b1[n] : 0.0f;
        #pragma unroll
        for (int r = 0; r < 4; ++r) {
            int node = nb + kq * 4 + r;
            PQ[(size_t)node * 1024 + n] = f2bf(acc[nt][r] + bias);
        }
    }
}

// ============ kernel 2: per-edge fused layer1(gather+add+relu) + layer2(MFMA) + layer3 ============
// grid 3125 x 256: each wave owns 64 edges as 4 m-tiles of a 16x16x32 MFMA.
// LDS-free: lane l gathers edge (m = l&15)'s A-fragment k-chunk directly from PQ.
// W2 B-frags amortized over 4 m-tiles -> W2 L2 traffic 6.55 GB -> 1.64 GB vs R1.
__global__ __launch_bounds__(256, 2) void edge_kernel(const short* __restrict__ PQ,
                                                      const int* __restrict__ ei,
                                                      const short* __restrict__ W2s,
                                                      const float* __restrict__ b2,
                                                      const float* __restrict__ W3,
                                                      const float* __restrict__ b3,
                                                      float* __restrict__ out) {
    int lane = threadIdx.x & 63;
    int w = threadIdx.x >> 6;
    int e0 = blockIdx.x * 256 + w * 64;
    int m = lane & 15;
    int kq = lane >> 4;

    // 64 col indices in lanes (idx_c), 64 row indices (idx_r); broadcast per tile via shfl
    int idx_c = ei[e0 + lane];
    int idx_r = ei[N_EDGES + e0 + lane];

    const short* pb[4];
    const short* qb[4];
    #pragma unroll
    for (int t = 0; t < 4; ++t) {
        int ce = __shfl(idx_c, t * 16 + m, 64);
        int re = __shfl(idx_r, t * 16 + m, 64);
        pb[t] = PQ + (size_t)ce * 1024 + kq * 8;          // P' half
        qb[t] = PQ + (size_t)re * 1024 + 512 + kq * 8;    // Q half
    }

    f32x4 acc[4][8];
    #pragma unroll
    for (int t = 0; t < 4; ++t)
        #pragma unroll
        for (int nt = 0; nt < 8; ++nt) acc[t][nt] = (f32x4){0.f, 0.f, 0.f, 0.f};

    #pragma unroll 1
    for (int kc = 0; kc < 16; ++kc) {
        bf16x8 b[8];
        #pragma unroll
        for (int nt = 0; nt < 8; ++nt)
            b[nt] = *(const bf16x8*)(W2s + (kc * 8 + nt) * 512 + lane * 8);
        #pragma unroll
        for (int t = 0; t < 4; ++t) {
            bf16x8 p = *(const bf16x8*)(pb[t] + kc * 32);
            bf16x8 q = *(const bf16x8*)(qb[t] + kc * 32);
            bf16x8 a;
            #pragma unroll
            for (int j = 0; j < 8; ++j) {
                float f = bf2f(p[j]) + bf2f(q[j]);
                f = f > 0.f ? f : 0.f;
                a[j] = f2bf(f);
            }
            #pragma unroll
            for (int nt = 0; nt < 8; ++nt)
                acc[t][nt] = __builtin_amdgcn_mfma_f32_16x16x32_bf16(a, b[nt], acc[t][nt], 0, 0, 0);
        }
    }

    // ---- epilogue: +b2, relu, dot with W3, +b3 (all f32) ----
    float b2v[8], w3v[8];
    #pragma unroll
    for (int nt = 0; nt < 8; ++nt) {
        b2v[nt] = b2[nt * 16 + m];
        w3v[nt] = W3[nt * 16 + m];
    }
    float b3s = b3[0];
    #pragma unroll
    for (int t = 0; t < 4; ++t) {
        float partial[4] = {0.f, 0.f, 0.f, 0.f};
        #pragma unroll
        for (int nt = 0; nt < 8; ++nt) {
            #pragma unroll
            for (int r = 0; r < 4; ++r) {
                float x2 = acc[t][nt][r] + b2v[nt];       // C row = kq*4+r, col = nt*16+m
                x2 = x2 > 0.f ? x2 : 0.f;
                partial[r] += x2 * w3v[nt];
            }
        }
        #pragma unroll
        for (int r = 0; r < 4; ++r) {
            #pragma unroll
            for (int off = 1; off < 16; off <<= 1)
                partial[r] += __shfl_xor(partial[r], off, 64);
            if (m == 0) out[e0 + t * 16 + kq * 4 + r] = partial[r] + b3s;
        }
    }
}

extern "C" void kernel_launch(void* const* d_in, const int* in_sizes, int n_in,
                              void* d_out, int out_size, void* d_ws, size_t ws_size,
                              hipStream_t stream) {
    const float* emb = (const float*)d_in[0];
    const int*   ei  = (const int*)d_in[1];
    const float* W1  = (const float*)d_in[2];
    const float* b1  = (const float*)d_in[3];
    const float* W2  = (const float*)d_in[4];
    const float* b2  = (const float*)d_in[5];
    const float* W3  = (const float*)d_in[6];
    const float* b3  = (const float*)d_in[7];
    float* out = (float*)d_out;

    short* PQ  = (short*)((char*)d_ws + PQ_OFF);
    short* W1s = (short*)((char*)d_ws + W1S_OFF);
    short* W2s = (short*)((char*)d_ws + W2S_OFF);

    swizzle_kernel<<<96, 256, 0, stream>>>(W1, W2, W1s, W2s);
    precompute_kernel<<<N_NODESC / 16, 256, 0, stream>>>(emb, W1s, b1, PQ);            // 3125 blocks
    edge_kernel<<<N_EDGES / 256, 256, 0, stream>>>(PQ, ei, W2s, b2, W3, b3, out);      // 3125 blocks
}